// Round 1
// baseline (253.630 us; speedup 1.0000x reference)
//
#include <hip/hip_runtime.h>
#include <hip/hip_bf16.h>
#include <stdint.h>

// Problem constants
#define B_  2
#define T_  2048
#define E_  1024
#define H_  16
#define D_  64
#define BH_ 32   // B_*H_

typedef unsigned short ushort_t;
typedef __attribute__((ext_vector_type(8))) short bfrag;   // 8 bf16 (4 VGPRs) MFMA A/B operand
typedef __attribute__((ext_vector_type(4))) float f32x4;   // MFMA C/D

__device__ __forceinline__ ushort_t f2b(float f) {  // fp32 -> bf16 (RTNE)
    uint32_t u = __builtin_bit_cast(uint32_t, f);
    u += 0x7fffu + ((u >> 16) & 1u);
    return (ushort_t)(u >> 16);
}
__device__ __forceinline__ float b2f(ushort_t h) {
    return __builtin_bit_cast(float, (uint32_t)h << 16);
}

typedef const __attribute__((address_space(1))) uint8_t* gas_t;
typedef __attribute__((address_space(3))) uint8_t* las_t;
__device__ __forceinline__ void gload_lds16(const void* g, void* l) {
    // async global->LDS, 16B per lane; LDS dest = wave-uniform base + lane*16
    __builtin_amdgcn_global_load_lds((gas_t)g, (las_t)l, 16, 0, 0);
}

// ---------------- cast x fp32 -> bf16 ----------------
__global__ __launch_bounds__(256) void cast_x_kernel(const float* __restrict__ in, ushort_t* __restrict__ out) {
    int i = (blockIdx.x * 256 + threadIdx.x) * 8;
    float4 a = *(const float4*)(in + i);
    float4 b = *(const float4*)(in + i + 4);
    ushort_t r[8] = {f2b(a.x), f2b(a.y), f2b(a.z), f2b(a.w), f2b(b.x), f2b(b.y), f2b(b.z), f2b(b.w)};
    *(uint4*)(out + i) = *(const uint4*)r;
}

// ------------- transpose+cast: in[R][C] fp32 -> out[C][R] bf16 -------------
__global__ __launch_bounds__(256) void transpose_cast_kernel(const float* __restrict__ in, ushort_t* __restrict__ out,
                                                             int R, int C) {
    __shared__ float tile[32][33];
    int tx = threadIdx.x, ty = threadIdx.y;
    int c0 = blockIdx.x * 32, r0 = blockIdx.y * 32;
#pragma unroll
    for (int i = 0; i < 4; ++i)
        tile[ty + i * 8][tx] = in[(size_t)(r0 + ty + i * 8) * C + c0 + tx];
    __syncthreads();
#pragma unroll
    for (int i = 0; i < 4; ++i)
        out[(size_t)(c0 + ty + i * 8) * R + r0 + tx] = f2b(tile[tx][ty + i * 8]);
}

// ---------------- GEMM1: qkv = x @ w_qkv + b, scatter to q/k/v [B,H,T,D] bf16 ----------------
// A [4096][1024] bf16 row-major, Bt [3072][1024] bf16 row-major (= w_qkv^T)
__global__ __launch_bounds__(256) void gemm_qkv_kernel(const ushort_t* __restrict__ A, const ushort_t* __restrict__ Bt,
                                                       const float* __restrict__ bias,
                                                       ushort_t* __restrict__ qw, ushort_t* __restrict__ kw,
                                                       ushort_t* __restrict__ vw) {
    const int K = 1024;
    __shared__ ushort_t As[128 * 32];
    __shared__ ushort_t Bs[128 * 32];
    int tid = threadIdx.x, lane = tid & 63, wid = tid >> 6;
    int bm = blockIdx.y, bn = blockIdx.x;
    int wm = wid >> 1, wn = wid & 1;
    int lm = lane & 15, lg = lane >> 4;
    f32x4 acc[4][4] = {};
    const ushort_t* ag = A + (size_t)(bm * 128 + (tid >> 2)) * K + (tid & 3) * 8;
    const ushort_t* bg = Bt + (size_t)(bn * 128 + (tid >> 2)) * K + (tid & 3) * 8;
    ushort_t* asd = As + wid * 512;
    ushort_t* bsd = Bs + wid * 512;
    for (int kt = 0; kt < K / 32; ++kt) {
        __syncthreads();
        gload_lds16(ag + kt * 32, asd);
        gload_lds16(ag + (size_t)64 * K + kt * 32, asd + 2048);
        gload_lds16(bg + kt * 32, bsd);
        gload_lds16(bg + (size_t)64 * K + kt * 32, bsd + 2048);
        __syncthreads();
        bfrag a[4], b[4];
#pragma unroll
        for (int mi = 0; mi < 4; ++mi) a[mi] = *(const bfrag*)&As[(wm * 64 + mi * 16 + lm) * 32 + lg * 8];
#pragma unroll
        for (int ni = 0; ni < 4; ++ni) b[ni] = *(const bfrag*)&Bs[(wn * 64 + ni * 16 + lm) * 32 + lg * 8];
#pragma unroll
        for (int mi = 0; mi < 4; ++mi)
#pragma unroll
            for (int ni = 0; ni < 4; ++ni)
                acc[mi][ni] = __builtin_amdgcn_mfma_f32_16x16x32_bf16(a[mi], b[ni], acc[mi][ni], 0, 0, 0);
    }
#pragma unroll
    for (int ni = 0; ni < 4; ++ni) {
        int c = bn * 128 + wn * 64 + ni * 16 + lm;
        int sel = c >> 10, e = c & 1023;
        int h = e >> 6, d = e & 63;
        ushort_t* dst = (sel == 0) ? qw : (sel == 1) ? kw : vw;
        float bb = bias[c];
#pragma unroll
        for (int mi = 0; mi < 4; ++mi) {
#pragma unroll
            for (int i = 0; i < 4; ++i) {
                int r = bm * 128 + wm * 64 + mi * 16 + lg * 4 + i;
                int b = r >> 11, t = r & (T_ - 1);
                dst[(size_t)((b * H_ + h) * T_ + t) * D_ + d] = f2b(acc[mi][ni][i] + bb);
            }
        }
    }
}

// ---------------- RoPE in-place on q,k [BH][T][D] bf16 ----------------
__global__ __launch_bounds__(256) void rope_kernel(ushort_t* __restrict__ qw, ushort_t* __restrict__ kw) {
    int id = blockIdx.x * 256 + threadIdx.x;   // [sel:1][bh:5][t:11][j:5]
    int j = id & 31;
    int t = (id >> 5) & (T_ - 1);
    int bh = (id >> 16) & 31;
    int sel = id >> 21;
    ushort_t* base = (sel ? kw : qw) + ((size_t)bh * T_ + t) * D_;
    float f0 = b2f(base[j]), f1 = b2f(base[j + 32]);
    float invf = expf(-(float)j * 0.2878231366242558f);   // ln(10000)/32
    float s, c;
    sincosf((float)t * invf, &s, &c);
    base[j]      = f2b(f0 * c - f1 * s);
    base[j + 32] = f2b(f1 * c + f0 * s);
}

// ---------------- causal flash attention ----------------
// grid (bh=32, qb=32); 4 waves, wave owns 16 Q rows; 32-key tiles
__global__ __launch_bounds__(256) void flash_kernel(const ushort_t* __restrict__ q, const ushort_t* __restrict__ k,
                                                    const ushort_t* __restrict__ v, ushort_t* __restrict__ o) {
    __shared__ ushort_t ks[32 * 64];
    __shared__ ushort_t vt[64 * 32];
    __shared__ ushort_t ps[4][16 * 32];
    int tid = threadIdx.x, lane = tid & 63, wid = tid >> 6;
    int bh = blockIdx.x, qb = blockIdx.y;
    int q0 = qb * 64;
    int lm = lane & 15, lg = lane >> 4;
    int b = bh >> 4, h = bh & 15;

    const ushort_t* qrow = q + ((size_t)bh * T_ + q0 + wid * 16 + lm) * D_;
    bfrag aq0 = *(const bfrag*)(qrow + lg * 8);
    bfrag aq1 = *(const bfrag*)(qrow + 32 + lg * 8);

    f32x4 accd[4] = {};
    float m_i[4] = {-1e30f, -1e30f, -1e30f, -1e30f};
    float l_i[4] = {0.f, 0.f, 0.f, 0.f};

    const ushort_t* kbase = k + (size_t)bh * T_ * D_;
    const ushort_t* vbase = v + (size_t)bh * T_ * D_;
    int vrow = tid >> 3, vd = (tid & 7) * 8;
    int nkt = (q0 >> 5) + 2;

    for (int ktile = 0; ktile < nkt; ++ktile) {
        __syncthreads();
        gload_lds16(kbase + (size_t)(ktile * 32) * 64 + tid * 8, ks + wid * 512);
        bfrag vv = *(const bfrag*)(vbase + (size_t)(ktile * 32 + vrow) * 64 + vd);
#pragma unroll
        for (int jj = 0; jj < 8; ++jj) vt[(vd + jj) * 32 + vrow] = (ushort_t)vv[jj];
        __syncthreads();

        f32x4 sacc[2];
#pragma unroll
        for (int sb = 0; sb < 2; ++sb) {
            bfrag bk0 = *(const bfrag*)&ks[(sb * 16 + lm) * 64 + lg * 8];
            bfrag bk1 = *(const bfrag*)&ks[(sb * 16 + lm) * 64 + 32 + lg * 8];
            f32x4 z = {};
            z = __builtin_amdgcn_mfma_f32_16x16x32_bf16(aq0, bk0, z, 0, 0, 0);
            sacc[sb] = __builtin_amdgcn_mfma_f32_16x16x32_bf16(aq1, bk1, z, 0, 0, 0);
        }
        bool anymask = (ktile * 32 + 31) > (q0 + wid * 16);
#pragma unroll
        for (int i = 0; i < 4; ++i) {
            int qg = q0 + wid * 16 + lg * 4 + i;
            float s0 = sacc[0][i] * 0.125f;
            float s1 = sacc[1][i] * 0.125f;
            if (anymask) {
                if (ktile * 32 + lm > qg) s0 = -1e30f;
                if (ktile * 32 + 16 + lm > qg) s1 = -1e30f;
            }
            float mt = fmaxf(s0, s1);
#pragma unroll
            for (int off = 1; off < 16; off <<= 1) mt = fmaxf(mt, __shfl_xor(mt, off));
            float mnew = fmaxf(m_i[i], mt);
            float corr = __expf(m_i[i] - mnew);
            float p0 = __expf(s0 - mnew);
            float p1 = __expf(s1 - mnew);
            float rs = p0 + p1;
#pragma unroll
            for (int off = 1; off < 16; off <<= 1) rs += __shfl_xor(rs, off);
            l_i[i] = l_i[i] * corr + rs;
            m_i[i] = mnew;
#pragma unroll
            for (int db = 0; db < 4; ++db) accd[db][i] *= corr;
            ps[wid][(lg * 4 + i) * 32 + lm] = f2b(p0);
            ps[wid][(lg * 4 + i) * 32 + 16 + lm] = f2b(p1);
        }
        __syncthreads();
        bfrag ap = *(const bfrag*)&ps[wid][lm * 32 + lg * 8];
#pragma unroll
        for (int db = 0; db < 4; ++db) {
            bfrag bv = *(const bfrag*)&vt[(db * 16 + lm) * 32 + lg * 8];
            accd[db] = __builtin_amdgcn_mfma_f32_16x16x32_bf16(ap, bv, accd[db], 0, 0, 0);
        }
    }
#pragma unroll
    for (int i = 0; i < 4; ++i) {
        float inv = 1.0f / l_i[i];
        int t = q0 + wid * 16 + lg * 4 + i;
        size_t ro = ((size_t)b * T_ + t) * E_ + h * D_;
#pragma unroll
        for (int db = 0; db < 4; ++db)
            o[ro + db * 16 + lm] = f2b(accd[db][i] * inv);
    }
}

// ---------------- GEMM2: out = ao @ w_out + b_out (fp32 out) ----------------
__global__ __launch_bounds__(256) void gemm_out_kernel(const ushort_t* __restrict__ A, const ushort_t* __restrict__ Bt,
                                                       const float* __restrict__ bias, float* __restrict__ out) {
    const int K = 1024;
    __shared__ ushort_t As[128 * 32];
    __shared__ ushort_t Bs[128 * 32];
    int tid = threadIdx.x, lane = tid & 63, wid = tid >> 6;
    int bm = blockIdx.y, bn = blockIdx.x;
    int wm = wid >> 1, wn = wid & 1;
    int lm = lane & 15, lg = lane >> 4;
    f32x4 acc[4][4] = {};
    const ushort_t* ag = A + (size_t)(bm * 128 + (tid >> 2)) * K + (tid & 3) * 8;
    const ushort_t* bg = Bt + (size_t)(bn * 128 + (tid >> 2)) * K + (tid & 3) * 8;
    ushort_t* asd = As + wid * 512;
    ushort_t* bsd = Bs + wid * 512;
    for (int kt = 0; kt < K / 32; ++kt) {
        __syncthreads();
        gload_lds16(ag + kt * 32, asd);
        gload_lds16(ag + (size_t)64 * K + kt * 32, asd + 2048);
        gload_lds16(bg + kt * 32, bsd);
        gload_lds16(bg + (size_t)64 * K + kt * 32, bsd + 2048);
        __syncthreads();
        bfrag a[4], b[4];
#pragma unroll
        for (int mi = 0; mi < 4; ++mi) a[mi] = *(const bfrag*)&As[(wm * 64 + mi * 16 + lm) * 32 + lg * 8];
#pragma unroll
        for (int ni = 0; ni < 4; ++ni) b[ni] = *(const bfrag*)&Bs[(wn * 64 + ni * 16 + lm) * 32 + lg * 8];
#pragma unroll
        for (int mi = 0; mi < 4; ++mi)
#pragma unroll
            for (int ni = 0; ni < 4; ++ni)
                acc[mi][ni] = __builtin_amdgcn_mfma_f32_16x16x32_bf16(a[mi], b[ni], acc[mi][ni], 0, 0, 0);
    }
#pragma unroll
    for (int ni = 0; ni < 4; ++ni) {
        int c = bn * 128 + wn * 64 + ni * 16 + lm;
        float bb = bias[c];
#pragma unroll
        for (int mi = 0; mi < 4; ++mi) {
#pragma unroll
            for (int i = 0; i < 4; ++i) {
                int r = bm * 128 + wm * 64 + mi * 16 + lg * 4 + i;
                out[(size_t)r * 1024 + c] = acc[mi][ni][i] + bb;
            }
        }
    }
}

extern "C" void kernel_launch(void* const* d_in, const int* in_sizes, int n_in,
                              void* d_out, int out_size, void* d_ws, size_t ws_size,
                              hipStream_t stream) {
    const float* x     = (const float*)d_in[0];
    const float* w_qkv = (const float*)d_in[1];
    const float* b_qkv = (const float*)d_in[2];
    const float* w_out = (const float*)d_in[3];
    const float* b_out = (const float*)d_in[4];
    float* out = (float*)d_out;

    ushort_t* ws    = (ushort_t*)d_ws;
    ushort_t* xb    = ws;                   // [4096][1024] bf16
    ushort_t* wqkvT = xb + 4194304;         // [3072][1024] bf16
    ushort_t* woutT = wqkvT + 3145728;      // [1024][1024] bf16
    ushort_t* qw    = woutT + 1048576;      // [BH][T][D]
    ushort_t* kw    = qw + 4194304;
    ushort_t* vw    = kw + 4194304;
    ushort_t* ao    = vw + 4194304;         // [4096][1024] bf16

    cast_x_kernel<<<2048, 256, 0, stream>>>(x, xb);
    transpose_cast_kernel<<<dim3(96, 32), dim3(32, 8), 0, stream>>>(w_qkv, wqkvT, 1024, 3072);
    transpose_cast_kernel<<<dim3(32, 32), dim3(32, 8), 0, stream>>>(w_out, woutT, 1024, 1024);
    gemm_qkv_kernel<<<dim3(24, 32), 256, 0, stream>>>(xb, wqkvT, b_qkv, qw, kw, vw);
    rope_kernel<<<16384, 256, 0, stream>>>(qw, kw);
    flash_kernel<<<dim3(32, 32), 256, 0, stream>>>(qw, kw, vw, ao);
    gemm_out_kernel<<<dim3(8, 32), 256, 0, stream>>>(ao, woutT, b_out, out);
}

// Round 2
// 190.998 us; speedup vs baseline: 1.3279x; 1.3279x over previous
//
#include <hip/hip_runtime.h>
#include <hip/hip_bf16.h>
#include <stdint.h>

// Problem constants
#define B_  2
#define T_  2048
#define E_  1024
#define H_  16
#define D_  64
#define BH_ 32   // B_*H_

typedef unsigned short ushort_t;
typedef __attribute__((ext_vector_type(8))) short bfrag;   // 8 bf16 (4 VGPRs) MFMA A/B operand
typedef __attribute__((ext_vector_type(4))) short s16x4;   // 4 bf16 (8B)
typedef __attribute__((ext_vector_type(4))) float f32x4;   // MFMA C/D

__device__ __forceinline__ ushort_t f2b(float f) {  // fp32 -> bf16 (RTNE)
    uint32_t u = __builtin_bit_cast(uint32_t, f);
    u += 0x7fffu + ((u >> 16) & 1u);
    return (ushort_t)(u >> 16);
}
__device__ __forceinline__ float b2f(ushort_t h) {
    return __builtin_bit_cast(float, (uint32_t)h << 16);
}
__device__ __forceinline__ float hexp2(float x) {   // v_exp_f32: D = 2^S0
    float r;
    asm volatile("v_exp_f32 %0, %1\n\ts_nop 1" : "=v"(r) : "v"(x));
    return r;
}

typedef const __attribute__((address_space(1))) uint8_t* gas_t;
typedef __attribute__((address_space(3))) uint8_t* las_t;
__device__ __forceinline__ void gload_lds16(const void* g, void* l) {
    __builtin_amdgcn_global_load_lds((gas_t)g, (las_t)l, 16, 0, 0);
}

// ---------------- cast x fp32 -> bf16 ----------------
__global__ __launch_bounds__(256) void cast_x_kernel(const float* __restrict__ in, ushort_t* __restrict__ out) {
    int i = (blockIdx.x * 256 + threadIdx.x) * 8;
    float4 a = *(const float4*)(in + i);
    float4 b = *(const float4*)(in + i + 4);
    ushort_t r[8] = {f2b(a.x), f2b(a.y), f2b(a.z), f2b(a.w), f2b(b.x), f2b(b.y), f2b(b.z), f2b(b.w)};
    *(uint4*)(out + i) = *(const uint4*)r;
}

// ------------- transpose+cast: in[R][C] fp32 -> out[C][R] bf16 -------------
__global__ __launch_bounds__(256) void transpose_cast_kernel(const float* __restrict__ in, ushort_t* __restrict__ out,
                                                             int R, int C) {
    __shared__ float tile[32][33];
    int tx = threadIdx.x, ty = threadIdx.y;
    int c0 = blockIdx.x * 32, r0 = blockIdx.y * 32;
#pragma unroll
    for (int i = 0; i < 4; ++i)
        tile[ty + i * 8][tx] = in[(size_t)(r0 + ty + i * 8) * C + c0 + tx];
    __syncthreads();
#pragma unroll
    for (int i = 0; i < 4; ++i)
        out[(size_t)(c0 + ty + i * 8) * R + r0 + tx] = f2b(tile[tx][ty + i * 8]);
}

// ---------------- GEMM1: qkv = x @ w_qkv + b ----------------
// q,k -> [BH][T][D];  v -> TRANSPOSED Vt [BH][D][T]
__global__ __launch_bounds__(256) void gemm_qkv_kernel(const ushort_t* __restrict__ A, const ushort_t* __restrict__ Bt,
                                                       const float* __restrict__ bias,
                                                       ushort_t* __restrict__ qw, ushort_t* __restrict__ kw,
                                                       ushort_t* __restrict__ vw) {
    const int K = 1024;
    __shared__ ushort_t As[128 * 32];
    __shared__ ushort_t Bs[128 * 32];
    int tid = threadIdx.x, lane = tid & 63, wid = tid >> 6;
    int bm = blockIdx.y, bn = blockIdx.x;
    int wm = wid >> 1, wn = wid & 1;
    int lm = lane & 15, lg = lane >> 4;
    f32x4 acc[4][4] = {};
    const ushort_t* ag = A + (size_t)(bm * 128 + (tid >> 2)) * K + (tid & 3) * 8;
    const ushort_t* bg = Bt + (size_t)(bn * 128 + (tid >> 2)) * K + (tid & 3) * 8;
    ushort_t* asd = As + wid * 512;
    ushort_t* bsd = Bs + wid * 512;
    for (int kt = 0; kt < K / 32; ++kt) {
        __syncthreads();
        gload_lds16(ag + kt * 32, asd);
        gload_lds16(ag + (size_t)64 * K + kt * 32, asd + 2048);
        gload_lds16(bg + kt * 32, bsd);
        gload_lds16(bg + (size_t)64 * K + kt * 32, bsd + 2048);
        __syncthreads();
        bfrag a[4], b[4];
#pragma unroll
        for (int mi = 0; mi < 4; ++mi) a[mi] = *(const bfrag*)&As[(wm * 64 + mi * 16 + lm) * 32 + lg * 8];
#pragma unroll
        for (int ni = 0; ni < 4; ++ni) b[ni] = *(const bfrag*)&Bs[(wn * 64 + ni * 16 + lm) * 32 + lg * 8];
#pragma unroll
        for (int mi = 0; mi < 4; ++mi)
#pragma unroll
            for (int ni = 0; ni < 4; ++ni)
                acc[mi][ni] = __builtin_amdgcn_mfma_f32_16x16x32_bf16(a[mi], b[ni], acc[mi][ni], 0, 0, 0);
    }
#pragma unroll
    for (int ni = 0; ni < 4; ++ni) {
        int c = bn * 128 + wn * 64 + ni * 16 + lm;
        int sel = c >> 10, e = c & 1023;
        int h = e >> 6, d = e & 63;
        float bb = bias[c];
        if (sel < 2) {
            ushort_t* dst = sel ? kw : qw;
#pragma unroll
            for (int mi = 0; mi < 4; ++mi) {
#pragma unroll
                for (int i = 0; i < 4; ++i) {
                    int r = bm * 128 + wm * 64 + mi * 16 + lg * 4 + i;
                    int b = r >> 11, t = r & (T_ - 1);
                    dst[(size_t)((b * H_ + h) * T_ + t) * D_ + d] = f2b(acc[mi][ni][i] + bb);
                }
            }
        } else {
#pragma unroll
            for (int mi = 0; mi < 4; ++mi) {
                int r = bm * 128 + wm * 64 + mi * 16 + lg * 4;
                int b = r >> 11, t = r & (T_ - 1);
                uint32_t lo = (uint32_t)f2b(acc[mi][ni][0] + bb) | ((uint32_t)f2b(acc[mi][ni][1] + bb) << 16);
                uint32_t hi = (uint32_t)f2b(acc[mi][ni][2] + bb) | ((uint32_t)f2b(acc[mi][ni][3] + bb) << 16);
                uint2 w; w.x = lo; w.y = hi;
                *(uint2*)&vw[((size_t)(b * H_ + h) * D_ + d) * T_ + t] = w;
            }
        }
    }
}

// ---------------- RoPE in-place on q,k [BH][T][D] bf16 ----------------
// q additionally scaled by 0.125 * log2(e) so flash can use exp2 directly
__global__ __launch_bounds__(256) void rope_kernel(ushort_t* __restrict__ qw, ushort_t* __restrict__ kw) {
    int id = blockIdx.x * 256 + threadIdx.x;   // [sel:1][bh:5][t:11][j:5]
    int j = id & 31;
    int t = (id >> 5) & (T_ - 1);
    int bh = (id >> 16) & 31;
    int sel = id >> 21;
    ushort_t* base = (sel ? kw : qw) + ((size_t)bh * T_ + t) * D_;
    float f0 = b2f(base[j]), f1 = b2f(base[j + 32]);
    float invf = expf(-(float)j * 0.2878231366242558f);   // ln(10000)/32
    float s, c;
    sincosf((float)t * invf, &s, &c);
    float scale = sel ? 1.0f : 0.18033688011112042f;      // q: 1/sqrt(64) * log2(e)
    base[j]      = f2b((f0 * c - f1 * s) * scale);
    base[j + 32] = f2b((f1 * c + f0 * s) * scale);
}

// ---------------- causal flash attention: no LDS, no barriers ----------------
// Each wave owns 32 Q rows (two 16-row subtiles). Swapped QK^T: st = mfma(K, Q)
// puts a full P column (fixed q = lane&15) in each lane -> in-register softmax.
// PV uses a permuted k-slot mapping matched by two b64 loads from Vt[bh][d][T].
__global__ __launch_bounds__(256) void flash_kernel(const ushort_t* __restrict__ q, const ushort_t* __restrict__ k,
                                                    const ushort_t* __restrict__ vt, ushort_t* __restrict__ o) {
    int tid = threadIdx.x, lane = tid & 63, wid = tid >> 6;
    int lm = lane & 15, lg = lane >> 4;
    // bijective XCD swizzle: XCD x handles bh 4x..4x+3; long/short qt pairing per block
    int X = blockIdx.x & 7, c = blockIdx.x >> 3;
    int bh = (X << 2) + (c >> 4);
    int base = (c & 15) * 2;
    int qt;
    if (wid == 0) qt = base;
    else if (wid == 1) qt = 63 - base;
    else if (wid == 2) qt = base + 1;
    else qt = 62 - base;
    int q0 = qt * 32;
    int b = bh >> 4, h = bh & 15;

    const ushort_t* qb = q + (size_t)bh * T_ * D_;
    const ushort_t* kb = k + (size_t)bh * T_ * D_;
    const ushort_t* vb = vt + (size_t)bh * D_ * T_;

    bfrag aq[2][2];
#pragma unroll
    for (int s = 0; s < 2; ++s)
#pragma unroll
        for (int hh = 0; hh < 2; ++hh)
            aq[s][hh] = *(const bfrag*)(qb + (size_t)(q0 + s * 16 + lm) * D_ + hh * 32 + lg * 8);

    f32x4 acc[2][4] = {};
    float m_s[2] = {-1e30f, -1e30f};
    float l_s[2] = {0.f, 0.f};

    int nkt = qt + 1;
    bfrag ka[2][2];
#pragma unroll
    for (int sb = 0; sb < 2; ++sb)
#pragma unroll
        for (int hh = 0; hh < 2; ++hh)
            ka[sb][hh] = *(const bfrag*)(kb + (size_t)(sb * 16 + lm) * D_ + hh * 32 + lg * 8);

    for (int t = 0; t < nkt; ++t) {
        int k0 = t * 32;
        // V loads for this tile (independent of softmax; latency hides under it)
        s16x4 v0[4], v1[4];
#pragma unroll
        for (int db = 0; db < 4; ++db) {
            const ushort_t* vr = vb + (size_t)(db * 16 + lm) * T_ + k0 + lg * 4;
            v0[db] = *(const s16x4*)vr;
            v1[db] = *(const s16x4*)(vr + 16);
        }
        // swapped QK^T: st[s][sb][i] = S^T[k = k0+16sb+4lg+i][q = q0+16s+lm] (log2 domain)
        f32x4 st[2][2];
        __builtin_amdgcn_s_setprio(1);
#pragma unroll
        for (int s = 0; s < 2; ++s)
#pragma unroll
            for (int sb = 0; sb < 2; ++sb) {
                f32x4 z = {};
                z = __builtin_amdgcn_mfma_f32_16x16x32_bf16(ka[sb][0], aq[s][0], z, 0, 0, 0);
                st[s][sb] = __builtin_amdgcn_mfma_f32_16x16x32_bf16(ka[sb][1], aq[s][1], z, 0, 0, 0);
            }
        __builtin_amdgcn_s_setprio(0);
        // prefetch next K tile
        if (t + 1 < nkt) {
#pragma unroll
            for (int sb = 0; sb < 2; ++sb)
#pragma unroll
                for (int hh = 0; hh < 2; ++hh)
                    ka[sb][hh] = *(const bfrag*)(kb + (size_t)(k0 + 32 + sb * 16 + lm) * D_ + hh * 32 + lg * 8);
        }
        bool last = (t == nkt - 1);
        uint32_t pb[2][4];
#pragma unroll
        for (int s = 0; s < 2; ++s) {
            int qg = q0 + s * 16 + lm;
            if (last) {
#pragma unroll
                for (int sb = 0; sb < 2; ++sb)
#pragma unroll
                    for (int i = 0; i < 4; ++i)
                        if (k0 + sb * 16 + lg * 4 + i > qg) st[s][sb][i] = -1e30f;
            }
            float t0 = fmaxf(fmaxf(st[s][0][0], st[s][0][1]), fmaxf(st[s][0][2], st[s][0][3]));
            float t1 = fmaxf(fmaxf(st[s][1][0], st[s][1][1]), fmaxf(st[s][1][2], st[s][1][3]));
            float tm = fmaxf(t0, t1);
            tm = fmaxf(tm, __shfl_xor(tm, 16));
            tm = fmaxf(tm, __shfl_xor(tm, 32));
            float mnew = fmaxf(m_s[s], tm);
            float corr = hexp2(m_s[s] - mnew);
            float p[2][4];
            float rs = 0.f;
#pragma unroll
            for (int sb = 0; sb < 2; ++sb)
#pragma unroll
                for (int i = 0; i < 4; ++i) {
                    p[sb][i] = hexp2(st[s][sb][i] - mnew);
                    rs += p[sb][i];
                }
            rs += __shfl_xor(rs, 16);
            rs += __shfl_xor(rs, 32);
            l_s[s] = l_s[s] * corr + rs;
            m_s[s] = mnew;
#pragma unroll
            for (int db = 0; db < 4; ++db) acc[s][db] *= corr;
            pb[s][0] = (uint32_t)f2b(p[0][0]) | ((uint32_t)f2b(p[0][1]) << 16);
            pb[s][1] = (uint32_t)f2b(p[0][2]) | ((uint32_t)f2b(p[0][3]) << 16);
            pb[s][2] = (uint32_t)f2b(p[1][0]) | ((uint32_t)f2b(p[1][1]) << 16);
            pb[s][3] = (uint32_t)f2b(p[1][2]) | ((uint32_t)f2b(p[1][3]) << 16);
        }
        // PV: acc^T[d][q] += V-frag * P-frag (shared k-slot permutation)
        __builtin_amdgcn_s_setprio(1);
#pragma unroll
        for (int s = 0; s < 2; ++s) {
            uint4 u4; u4.x = pb[s][0]; u4.y = pb[s][1]; u4.z = pb[s][2]; u4.w = pb[s][3];
            bfrag pf = __builtin_bit_cast(bfrag, u4);
#pragma unroll
            for (int db = 0; db < 4; ++db) {
                bfrag va = __builtin_shufflevector(v0[db], v1[db], 0, 1, 2, 3, 4, 5, 6, 7);
                acc[s][db] = __builtin_amdgcn_mfma_f32_16x16x32_bf16(va, pf, acc[s][db], 0, 0, 0);
            }
        }
        __builtin_amdgcn_s_setprio(0);
    }
    // epilogue: O^T[d][q] -> o[b][t][h*64+d]
#pragma unroll
    for (int s = 0; s < 2; ++s) {
        float inv = 1.0f / l_s[s];
        int tq = q0 + s * 16 + lm;
        size_t ro = ((size_t)b * T_ + tq) * E_ + h * D_;
#pragma unroll
        for (int db = 0; db < 4; ++db) {
            uint32_t lo = (uint32_t)f2b(acc[s][db][0] * inv) | ((uint32_t)f2b(acc[s][db][1] * inv) << 16);
            uint32_t hi = (uint32_t)f2b(acc[s][db][2] * inv) | ((uint32_t)f2b(acc[s][db][3] * inv) << 16);
            uint2 w; w.x = lo; w.y = hi;
            *(uint2*)(o + ro + db * 16 + lg * 4) = w;
        }
    }
}

// ---------------- GEMM2: out = ao @ w_out + b_out (fp32 out) ----------------
__global__ __launch_bounds__(256) void gemm_out_kernel(const ushort_t* __restrict__ A, const ushort_t* __restrict__ Bt,
                                                       const float* __restrict__ bias, float* __restrict__ out) {
    const int K = 1024;
    __shared__ ushort_t As[128 * 32];
    __shared__ ushort_t Bs[128 * 32];
    int tid = threadIdx.x, lane = tid & 63, wid = tid >> 6;
    int bm = blockIdx.y, bn = blockIdx.x;
    int wm = wid >> 1, wn = wid & 1;
    int lm = lane & 15, lg = lane >> 4;
    f32x4 acc[4][4] = {};
    const ushort_t* ag = A + (size_t)(bm * 128 + (tid >> 2)) * K + (tid & 3) * 8;
    const ushort_t* bg = Bt + (size_t)(bn * 128 + (tid >> 2)) * K + (tid & 3) * 8;
    ushort_t* asd = As + wid * 512;
    ushort_t* bsd = Bs + wid * 512;
    for (int kt = 0; kt < K / 32; ++kt) {
        __syncthreads();
        gload_lds16(ag + kt * 32, asd);
        gload_lds16(ag + (size_t)64 * K + kt * 32, asd + 2048);
        gload_lds16(bg + kt * 32, bsd);
        gload_lds16(bg + (size_t)64 * K + kt * 32, bsd + 2048);
        __syncthreads();
        bfrag a[4], b[4];
#pragma unroll
        for (int mi = 0; mi < 4; ++mi) a[mi] = *(const bfrag*)&As[(wm * 64 + mi * 16 + lm) * 32 + lg * 8];
#pragma unroll
        for (int ni = 0; ni < 4; ++ni) b[ni] = *(const bfrag*)&Bs[(wn * 64 + ni * 16 + lm) * 32 + lg * 8];
#pragma unroll
        for (int mi = 0; mi < 4; ++mi)
#pragma unroll
            for (int ni = 0; ni < 4; ++ni)
                acc[mi][ni] = __builtin_amdgcn_mfma_f32_16x16x32_bf16(a[mi], b[ni], acc[mi][ni], 0, 0, 0);
    }
#pragma unroll
    for (int ni = 0; ni < 4; ++ni) {
        int c = bn * 128 + wn * 64 + ni * 16 + lm;
        float bb = bias[c];
#pragma unroll
        for (int mi = 0; mi < 4; ++mi) {
#pragma unroll
            for (int i = 0; i < 4; ++i) {
                int r = bm * 128 + wm * 64 + mi * 16 + lg * 4 + i;
                out[(size_t)r * 1024 + c] = acc[mi][ni][i] + bb;
            }
        }
    }
}

extern "C" void kernel_launch(void* const* d_in, const int* in_sizes, int n_in,
                              void* d_out, int out_size, void* d_ws, size_t ws_size,
                              hipStream_t stream) {
    const float* x     = (const float*)d_in[0];
    const float* w_qkv = (const float*)d_in[1];
    const float* b_qkv = (const float*)d_in[2];
    const float* w_out = (const float*)d_in[3];
    const float* b_out = (const float*)d_in[4];
    float* out = (float*)d_out;

    ushort_t* ws    = (ushort_t*)d_ws;
    ushort_t* xb    = ws;                   // [4096][1024] bf16
    ushort_t* wqkvT = xb + 4194304;         // [3072][1024] bf16
    ushort_t* woutT = wqkvT + 3145728;      // [1024][1024] bf16
    ushort_t* qw    = woutT + 1048576;      // [BH][T][D]
    ushort_t* kw    = qw + 4194304;
    ushort_t* vw    = kw + 4194304;         // Vt: [BH][D][T]
    ushort_t* ao    = vw + 4194304;         // [4096][1024] bf16

    cast_x_kernel<<<2048, 256, 0, stream>>>(x, xb);
    transpose_cast_kernel<<<dim3(96, 32), dim3(32, 8), 0, stream>>>(w_qkv, wqkvT, 1024, 3072);
    transpose_cast_kernel<<<dim3(32, 32), dim3(32, 8), 0, stream>>>(w_out, woutT, 1024, 1024);
    gemm_qkv_kernel<<<dim3(24, 32), 256, 0, stream>>>(xb, wqkvT, b_qkv, qw, kw, vw);
    rope_kernel<<<16384, 256, 0, stream>>>(qw, kw);
    flash_kernel<<<dim3(512), 256, 0, stream>>>(qw, kw, vw, ao);
    gemm_out_kernel<<<dim3(8, 32), 256, 0, stream>>>(ao, woutT, b_out, out);
}